// Round 1
// baseline (330.310 us; speedup 1.0000x reference)
//
#include <hip/hip_runtime.h>
#include <hip/hip_bf16.h>

// Problem constants (fixed by reference)
#define BB 32
#define DD 64
#define HH 64
#define WW 64
#define KK 512
#define HWHW (HH * WW)          // 4096
#define NPOS (BB * HWHW)        // 131072
#define NELEM (NPOS * DD)       // 8388608
#define LOSS_SCALE (1.2f / 8388608.f)

// ---------------------------------------------------------------------------
// Kernel 1: e2half[k] = 0.5 * sum_d emb[k][d]^2
// ---------------------------------------------------------------------------
__global__ void vq_e2_kernel(const float* __restrict__ emb,
                             float* __restrict__ e2half) {
    int k = blockIdx.x * blockDim.x + threadIdx.x;
    if (k >= KK) return;
    const float* ek = emb + k * DD;
    float s0 = 0.f, s1 = 0.f, s2 = 0.f, s3 = 0.f;
#pragma unroll
    for (int d = 0; d < DD; d += 4) {
        s0 = fmaf(ek[d],     ek[d],     s0);
        s1 = fmaf(ek[d + 1], ek[d + 1], s1);
        s2 = fmaf(ek[d + 2], ek[d + 2], s2);
        s3 = fmaf(ek[d + 3], ek[d + 3], s3);
    }
    e2half[k] = 0.5f * ((s0 + s1) + (s2 + s3));
}

// ---------------------------------------------------------------------------
// Kernel 2: main VQ kernel. One thread = one spatial position.
//   - x[64] held in VGPRs (NCHW strided load, coalesced across threads per d)
//   - k-loop: emb[k][*] is wave-uniform -> scalar loads (s_load), inner loop
//     is pure v_fmac_f32 with SGPR operand. score = x.e - e2/2, argmax.
//   - epilogue: gather winner, write st (== quant_out) back NCHW, fused
//     loss partial sum -> block reduce -> atomicAdd.
// ---------------------------------------------------------------------------
__global__ __launch_bounds__(256) void vq_main_kernel(
        const float* __restrict__ feat,
        const float* __restrict__ emb,
        const float* __restrict__ e2half,
        float* __restrict__ out,
        float* __restrict__ loss) {
    const int n  = blockIdx.x * 256 + threadIdx.x;   // position 0..131071
    const int b  = n >> 12;                          // n / 4096
    const int hw = n & (HWHW - 1);

    const float* xp = feat + (size_t)b * DD * HWHW + hw;
    float x[DD];
#pragma unroll
    for (int d = 0; d < DD; ++d) x[d] = xp[(size_t)d * HWHW];

    float best  = -3.0e38f;
    int   bidx  = 0;

#pragma unroll 2
    for (int k = 0; k < KK; ++k) {
        const float* ek = emb + k * DD;              // uniform -> s_load
        float s0 = 0.f, s1 = 0.f, s2 = 0.f, s3 = 0.f;
#pragma unroll
        for (int d = 0; d < DD; d += 4) {
            s0 = fmaf(x[d],     ek[d],     s0);
            s1 = fmaf(x[d + 1], ek[d + 1], s1);
            s2 = fmaf(x[d + 2], ek[d + 2], s2);
            s3 = fmaf(x[d + 3], ek[d + 3], s3);
        }
        float s = ((s0 + s1) + (s2 + s3)) - e2half[k];
        // strict > : first max index wins ties == jnp.argmin first-min
        if (s > best) { best = s; bidx = k; }
    }

    // Epilogue: gather winning code, write NCHW, accumulate loss
    const float* eb = emb + bidx * DD;               // divergent, L1/L2-hot
    float* op = out + (size_t)b * DD * HWHW + hw;
    float lsum = 0.f;
#pragma unroll
    for (int d = 0; d < DD; ++d) {
        float q    = eb[d];
        float diff = q - x[d];
        lsum = fmaf(diff, diff, lsum);
        op[(size_t)d * HWHW] = q;
    }

    // wave(64) shuffle reduce
#pragma unroll
    for (int off = 32; off > 0; off >>= 1)
        lsum += __shfl_down(lsum, off, 64);

    __shared__ float wsum[4];
    const int lane = threadIdx.x & 63;
    const int wid  = threadIdx.x >> 6;
    if (lane == 0) wsum[wid] = lsum;
    __syncthreads();
    if (threadIdx.x == 0) {
        float s = (wsum[0] + wsum[1]) + (wsum[2] + wsum[3]);
        atomicAdd(loss, s * LOSS_SCALE);
    }
}

// ---------------------------------------------------------------------------
extern "C" void kernel_launch(void* const* d_in, const int* in_sizes, int n_in,
                              void* d_out, int out_size, void* d_ws, size_t ws_size,
                              hipStream_t stream) {
    const float* feat = (const float*)d_in[0];   // (32,64,64,64) fp32
    const float* emb  = (const float*)d_in[1];   // (512,64) fp32
    float* out  = (float*)d_out;                 // [0..8388607] = st, [8388608] = loss
    float* loss = out + NELEM;
    float* e2half = (float*)d_ws;                // 512 floats scratch

    // zero the loss accumulator (d_out is poisoned 0xAA before every launch)
    hipMemsetAsync(loss, 0, sizeof(float), stream);

    vq_e2_kernel<<<dim3((KK + 255) / 256), dim3(256), 0, stream>>>(emb, e2half);

    vq_main_kernel<<<dim3(NPOS / 256), dim3(256), 0, stream>>>(
        feat, emb, e2half, out, loss);
}

// Round 3
// 165.822 us; speedup vs baseline: 1.9920x; 1.9920x over previous
//
#include <hip/hip_runtime.h>
#include <hip/hip_bf16.h>

// Problem constants (fixed by reference)
#define BB 32
#define DD 64
#define HWHW 4096
#define NPOS 131072
#define NELEM (NPOS * DD)          // 8388608
#define KK 512
#define LOSS_SCALE (1.2f / 8388608.f)
#define DELTA 1.5f                  // >= 2*eps(bf16 dot) with big margin
#define QCAP 6144

typedef __attribute__((ext_vector_type(8))) short short8v;   // 8 bf16
typedef __attribute__((ext_vector_type(4))) float float4v;   // MFMA acc

__device__ inline unsigned short f2bf(float f) {             // fp32->bf16 RNE
    unsigned u = __float_as_uint(f);
    unsigned r = u + 0x7FFFu + ((u >> 16) & 1u);
    return (unsigned short)(r >> 16);
}
__device__ inline float bf2f(unsigned short s) {
    return __uint_as_float(((unsigned)s) << 16);
}
__device__ inline unsigned f2o(float f) {                    // order-preserving f32->u32
    unsigned u = __float_as_uint(f);
    return ((int)u < 0) ? ~u : (u | 0x80000000u);
}

// ---------------------------------------------------------------------------
// Prep: E fp32 -> bf16 (RNE) into ws; e2half[k] = 0.5*|e_k|^2 fp32.
// 16 threads per codebook row, fully coalesced float4 loads.
// ---------------------------------------------------------------------------
__global__ __launch_bounds__(256) void vq_prep(const float* __restrict__ emb,
                                               unsigned short* __restrict__ ebf,
                                               float* __restrict__ e2h) {
    const int t = blockIdx.x * 256 + threadIdx.x;   // 0..8191
    const int row = t >> 4, c = t & 15;
    const float4 v = *(const float4*)(emb + row * DD + c * 4);
    unsigned u0 = (unsigned)f2bf(v.x) | ((unsigned)f2bf(v.y) << 16);
    unsigned u1 = (unsigned)f2bf(v.z) | ((unsigned)f2bf(v.w) << 16);
    *(uint2*)(ebf + row * DD + c * 4) = make_uint2(u0, u1);
    float p = v.x * v.x + v.y * v.y + v.z * v.z + v.w * v.w;
    p += __shfl_xor(p, 1, 64); p += __shfl_xor(p, 2, 64);
    p += __shfl_xor(p, 4, 64); p += __shfl_xor(p, 8, 64);
    if (c == 0) e2h[row] = 0.5f * p;
}

// ---------------------------------------------------------------------------
// Main: block = 512 positions (grid 256 = 1 block/CU), 4 waves x 8 pos-tiles.
// Scores S^T = E_bf16 * X_bf16^T via mfma_f32_16x16x32_bf16, with C-operand
// pre-loaded to -e2half (C/D row == code, and C layout per lane is exactly
// the 4 codes lg*4+r -> the e2 vector we already hold).
//   A-frag (E): lane reads 16B at ebf[row=ct*16+(l&15)][ (l>>4)*8 + h*32 ],
//   B-frag (X): elem j <-> d = h*32+(l>>4)*8+j  (same k-mapping as A -> any
//   internal k-permutation cancels).
//   C/D: col = l&15 = position, row = (l>>4)*4 + r = code-in-tile (m89).
// Pass1: per-position max score. Pass2: bitwise-identical recompute, enqueue
// codes within DELTA of max. Drain: fp32 rescore, atomicMax packed key
// (monotone float encoding | (511-k) => first-min-index tie rule).
// ---------------------------------------------------------------------------
__global__ __launch_bounds__(256, 1) void vq_main(
        const float* __restrict__ feat,
        const float* __restrict__ emb,
        const unsigned short* __restrict__ ebf,
        const float* __restrict__ e2h,
        float* __restrict__ out,
        float* __restrict__ loss) {

    __shared__ unsigned long long sbest[512];
    __shared__ unsigned qbuf[QCAP];
    __shared__ unsigned qcnt;
    __shared__ float wsum[4];

    const int tid = threadIdx.x;
    const int wid = tid >> 6, lane = tid & 63;
    const int l15 = lane & 15, lg = lane >> 4;

    sbest[tid] = 0ull; sbest[tid + 256] = 0ull;
    if (tid == 0) qcnt = 0u;

    const int pbase = blockIdx.x * 512;
    const int b     = pbase >> 12;
    const int hwb   = pbase & 4095;
    const float* featB = feat + (size_t)b * DD * HWHW;
    float*       outB  = out  + (size_t)b * DD * HWHW;
    const int wbase = wid * 128;

    // ---- build B-frags: x bf16, 8 pos-tiles x 2 k-halves ----
    short8v bx[8][2];
#pragma unroll
    for (int pt = 0; pt < 8; ++pt) {
        const int hw = hwb + wbase + pt * 16 + l15;
#pragma unroll
        for (int h = 0; h < 2; ++h) {
            float xv[8];
#pragma unroll
            for (int j = 0; j < 8; ++j) {
                const int d = h * 32 + lg * 8 + j;
                xv[j] = featB[(size_t)d * HWHW + hw];
            }
            short8v s;
#pragma unroll
            for (int j = 0; j < 8; ++j) s[j] = (short)f2bf(xv[j]);
            bx[pt][h] = s;
        }
    }

    __syncthreads();   // LDS init visible

    const char* ebfB = (const char*)ebf;

    // ---- pass 1: per-position max score ----
    float M[8];
#pragma unroll
    for (int pt = 0; pt < 8; ++pt) M[pt] = -3.0e38f;

    short8v a0n = *(const short8v*)(ebfB + l15 * 128 + lg * 16);
    short8v a1n = *(const short8v*)(ebfB + l15 * 128 + 64 + lg * 16);
    float4v e2n = *(const float4v*)(e2h + lg * 4);

    for (int ct = 0; ct < 32; ++ct) {
        const short8v a0c = a0n, a1c = a1n;
        float4v nege2;
#pragma unroll
        for (int r = 0; r < 4; ++r) nege2[r] = -e2n[r];
        if (ct < 31) {
            const char* p = ebfB + ((ct + 1) * 16 + l15) * 128 + lg * 16;
            a0n = *(const short8v*)p;
            a1n = *(const short8v*)(p + 64);
            e2n = *(const float4v*)(e2h + (ct + 1) * 16 + lg * 4);
        }
        float4v acc[8];
#pragma unroll
        for (int pt = 0; pt < 8; ++pt)
            acc[pt] = __builtin_amdgcn_mfma_f32_16x16x32_bf16(a0c, bx[pt][0], nege2, 0, 0, 0);
#pragma unroll
        for (int pt = 0; pt < 8; ++pt)
            acc[pt] = __builtin_amdgcn_mfma_f32_16x16x32_bf16(a1c, bx[pt][1], acc[pt], 0, 0, 0);
#pragma unroll
        for (int pt = 0; pt < 8; ++pt) {
            const float m01 = fmaxf(acc[pt][0], acc[pt][1]);
            const float m23 = fmaxf(acc[pt][2], acc[pt][3]);
            M[pt] = fmaxf(M[pt], fmaxf(m01, m23));
        }
    }

    // ---- merge across the 4 lanes holding the same position column ----
    float thr[8];
#pragma unroll
    for (int pt = 0; pt < 8; ++pt) {
        float m = M[pt];
        m = fmaxf(m, __shfl_xor(m, 16, 64));
        m = fmaxf(m, __shfl_xor(m, 32, 64));
        thr[pt] = m - DELTA;
    }

    // ---- pass 2: bitwise-identical recompute, enqueue candidates ----
    a0n = *(const short8v*)(ebfB + l15 * 128 + lg * 16);
    a1n = *(const short8v*)(ebfB + l15 * 128 + 64 + lg * 16);
    e2n = *(const float4v*)(e2h + lg * 4);

    for (int ct = 0; ct < 32; ++ct) {
        const short8v a0c = a0n, a1c = a1n;
        float4v nege2;
#pragma unroll
        for (int r = 0; r < 4; ++r) nege2[r] = -e2n[r];
        if (ct < 31) {
            const char* p = ebfB + ((ct + 1) * 16 + l15) * 128 + lg * 16;
            a0n = *(const short8v*)p;
            a1n = *(const short8v*)(p + 64);
            e2n = *(const float4v*)(e2h + (ct + 1) * 16 + lg * 4);
        }
        float4v acc[8];
#pragma unroll
        for (int pt = 0; pt < 8; ++pt)
            acc[pt] = __builtin_amdgcn_mfma_f32_16x16x32_bf16(a0c, bx[pt][0], nege2, 0, 0, 0);
#pragma unroll
        for (int pt = 0; pt < 8; ++pt)
            acc[pt] = __builtin_amdgcn_mfma_f32_16x16x32_bf16(a1c, bx[pt][1], acc[pt], 0, 0, 0);
#pragma unroll
        for (int pt = 0; pt < 8; ++pt) {
            const float m01 = fmaxf(acc[pt][0], acc[pt][1]);
            const float m23 = fmaxf(acc[pt][2], acc[pt][3]);
            const float mx  = fmaxf(m01, m23);
            if (__any(mx >= thr[pt])) {
#pragma unroll
                for (int r = 0; r < 4; ++r) {
                    if (acc[pt][r] >= thr[pt]) {
                        const unsigned idx  = atomicAdd(&qcnt, 1u);
                        const unsigned code = (unsigned)(ct * 16 + lg * 4 + r);
                        const unsigned pos  = (unsigned)(wbase + pt * 16 + l15);
                        if (idx < QCAP) qbuf[idx] = (pos << 9) | code;
                    }
                }
            }
        }
    }

    __syncthreads();

    // ---- drain: fp32 rescore of candidates, resolve winner per position ----
    const unsigned nq = min(qcnt, (unsigned)QCAP);
    for (unsigned i = tid; i < nq; i += 256) {
        const unsigned e = qbuf[i];
        const unsigned p = e >> 9, k = e & 511u;
        const float* er = emb + k * DD;
        float a0 = 0.f, a1 = 0.f, a2 = 0.f, a3 = 0.f;
#pragma unroll
        for (int d = 0; d < DD; d += 4) {
            a0 = fmaf(featB[(size_t)(d    ) * HWHW + hwb + p], er[d    ], a0);
            a1 = fmaf(featB[(size_t)(d + 1) * HWHW + hwb + p], er[d + 1], a1);
            a2 = fmaf(featB[(size_t)(d + 2) * HWHW + hwb + p], er[d + 2], a2);
            a3 = fmaf(featB[(size_t)(d + 3) * HWHW + hwb + p], er[d + 3], a3);
        }
        const float sc = ((a0 + a1) + (a2 + a3)) - e2h[k];
        const unsigned long long key =
            ((unsigned long long)f2o(sc) << 32) | (unsigned long long)(511u - k);
        atomicMax(&sbest[p], key);   // ties -> larger (511-k) -> smaller k (first-min)
    }

    __syncthreads();

    // ---- epilogue: st = e[k*] (exact), loss from in-register bf16 x ----
    float lsum = 0.f;
#pragma unroll
    for (int pt = 0; pt < 8; ++pt) {
        const int pl = wbase + pt * 16 + l15;
        const int hw = hwb + pl;
        const unsigned long long key = sbest[pl];
        const unsigned k = 511u - (unsigned)key;
        const float* er = emb + k * DD;
#pragma unroll
        for (int h = 0; h < 2; ++h) {
            const short8v xs = bx[pt][h];
#pragma unroll
            for (int jj = 0; jj < 2; ++jj) {
                const float4v ev = *(const float4v*)(er + h * 32 + lg * 8 + jj * 4);
#pragma unroll
                for (int c = 0; c < 4; ++c) {
                    const int j = jj * 4 + c;
                    const int d = h * 32 + lg * 8 + j;
                    const float q = ev[c];
                    outB[(size_t)d * HWHW + hw] = q;
                    const float diff = q - bf2f((unsigned short)xs[j]);
                    lsum = fmaf(diff, diff, lsum);
                }
            }
        }
    }

#pragma unroll
    for (int off = 32; off > 0; off >>= 1) lsum += __shfl_down(lsum, off, 64);
    if (lane == 0) wsum[wid] = lsum;
    __syncthreads();
    if (tid == 0)
        atomicAdd(loss, (wsum[0] + wsum[1] + wsum[2] + wsum[3]) * LOSS_SCALE);
}

// ---------------------------------------------------------------------------
extern "C" void kernel_launch(void* const* d_in, const int* in_sizes, int n_in,
                              void* d_out, int out_size, void* d_ws, size_t ws_size,
                              hipStream_t stream) {
    const float* feat = (const float*)d_in[0];   // (32,64,64,64) fp32
    const float* emb  = (const float*)d_in[1];   // (512,64) fp32
    float* out  = (float*)d_out;                 // [0..NELEM) = st, [NELEM] = loss
    float* loss = out + NELEM;

    unsigned short* ebf = (unsigned short*)d_ws;                 // 64 KiB bf16 codebook
    float*          e2h = (float*)((char*)d_ws + 64 * 1024);     // 2 KiB

    hipMemsetAsync(loss, 0, sizeof(float), stream);
    vq_prep<<<dim3(32), dim3(256), 0, stream>>>(emb, ebf, e2h);
    vq_main<<<dim3(256), dim3(256), 0, stream>>>(feat, emb, ebf, e2h, out, loss);
}